// Round 7
// baseline (156.664 us; speedup 1.0000x reference)
//
#include <hip/hip_runtime.h>

// B=8, H=W=1024, N=4096, R=8 -> d=17, patch=289, out (B,N,578) f32.
// p[b,n, which, j] = img_which[b, my + j%17 - 8, mx + j/17 - 8] (zero-pad OOB),
// each 289-vector normalized: (p - mean) / (std_ddof1 + 1e-4).
//
// R6 post-mortem: unordered prefetch = +33MB traffic, no latency gain.
// Read side is locality-limited random-line scatter (~3.6 vs 6.4 TB/s).
// R7: spatially BIN-SORT the 65536 independent patches (64x64-px bins) so
// waves processing neighbors run together -> line sharing in L2/LLC, DRAM row
// locality. Aux: zero->count->scan->scatter into d_ws, then gather in sorted
// order (R4 body fusing two sorted patches/wave) + XCD-chunk swizzle.

#define IMG_H 1024
#define IMG_W 1024
#define HW (IMG_H * IMG_W)
#define DPATCH 17
#define NPATCH 289
#define RAD 8
#define LROW 20               // LDS row stride (5 float4 chunks, 16B aligned)
#define PLANE (DPATCH * LROW) // 340 floats per patch plane
#define NPAIRS 32768
#define NPT 65536             // total patches (pairs x 2 images)
#define NBINS 4096            // 8 b x 2 which x 16 x 16 spatial (64px bins)

typedef float float4v __attribute__((ext_vector_type(4)));
typedef float float2v __attribute__((ext_vector_type(2)));

// ---------------- binning helpers ----------------
__device__ __forceinline__ int patch_bin(const int* __restrict__ matches, int t) {
    const int pair = t >> 1, which = t & 1;
    const int2 mm = *(const int2*)(matches + pair * 4 + (which << 1));
    const int b = pair >> 12;
    return (((b << 1) | which) << 8) | ((mm.y >> 6) << 4) | (mm.x >> 6);
}

__global__ void zero_counts(unsigned* __restrict__ cnt) {
    cnt[blockIdx.x * blockDim.x + threadIdx.x] = 0u;
}

__global__ void count_bins(const int* __restrict__ matches,
                           unsigned* __restrict__ cnt) {
    const int t = blockIdx.x * blockDim.x + threadIdx.x;   // 8B-coalesced loads
    atomicAdd(&cnt[patch_bin(matches, t)], 1u);
}

// exclusive prefix sum over 4096 counts -> cursor (single block, 256 threads)
__global__ void scan_bins(const unsigned* __restrict__ cnt,
                          unsigned* __restrict__ cursor) {
    __shared__ unsigned sh[256];
    const int t = threadIdx.x;
    unsigned loc[16];
    unsigned s = 0;
#pragma unroll
    for (int i = 0; i < 16; ++i) { loc[i] = cnt[t * 16 + i]; s += loc[i]; }
    sh[t] = s;
    __syncthreads();
    for (int off = 1; off < 256; off <<= 1) {   // Hillis-Steele inclusive
        const unsigned v = (t >= off) ? sh[t - off] : 0u;
        __syncthreads();
        sh[t] += v;
        __syncthreads();
    }
    unsigned run = sh[t] - s;                   // exclusive over thread chunks
#pragma unroll
    for (int i = 0; i < 16; ++i) { cursor[t * 16 + i] = run; run += loc[i]; }
}

__global__ void scatter_ids(const int* __restrict__ matches,
                            unsigned* __restrict__ cursor,
                            unsigned* __restrict__ sorted) {
    const int t = blockIdx.x * blockDim.x + threadIdx.x;
    const unsigned pos = atomicAdd(&cursor[patch_bin(matches, t)], 1u);
    sorted[pos] = (unsigned)t;
}

// ---------------- main gather kernel (sorted order) ----------------
__global__ __launch_bounds__(256) void extract_patch_sorted(
    const float* __restrict__ img1,
    const float* __restrict__ img2,
    const int* __restrict__ matches,
    const unsigned* __restrict__ sorted,
    float* __restrict__ out)
{
    __shared__ __align__(16) float lds[4][2 * PLANE];  // per-wave private

    const int lane  = threadIdx.x & 63;
    const int wslot = __builtin_amdgcn_readfirstlane(threadIdx.x >> 6);
    // XCD-chunk swizzle (8192 blocks, 8 XCDs, 1024 blocks/XCD): consecutive
    // sorted work stays on one XCD so bin-mates share that XCD's L2.
    const int blk = ((blockIdx.x & 7) << 10) + (blockIdx.x >> 3);
    const int w   = blk * 4 + wslot;            // 0 .. 32767

    // two (bin-adjacent) patches per wave; scalar loads
    const int tA = (int)sorted[2 * w];
    const int tB = (int)sorted[2 * w + 1];
    const int pairA = tA >> 1, whichA = tA & 1;
    const int pairB = tB >> 1, whichB = tB & 1;
    const int2 mmA = *(const int2*)(matches + pairA * 4 + (whichA << 1));
    const int2 mmB = *(const int2*)(matches + pairB * 4 + (whichB << 1));
    const float* __restrict__ imgA =
        (whichA ? img2 : img1) + (size_t)(pairA >> 12) * HW;
    const float* __restrict__ imgB =
        (whichB ? img2 : img1) + (size_t)(pairB >> 12) * HW;

    float* __restrict__ lbase = &lds[wslot][0];
    float sA = 0.f, qA = 0.f, sB = 0.f, qB = 0.f;

    // gather one slot u = a*5 + q of one patch: row my+a-8, cols mx+4q-8..+3
    auto gather = [&](int u, const float* __restrict__ imgp, int mx, int my,
                      float* __restrict__ ldst, float& ssum, float& ssq) {
        const int a  = u / 5;                 // magic-mul
        const int q  = u - a * 5;
        const int iy = my + a - RAD;
        const int cb = mx + (q << 2) - RAD;
        float4v vv = {0.f, 0.f, 0.f, 0.f};
        const bool rowok = ((unsigned)iy < IMG_H);
        if (rowok && cb >= 0 && (cb + 3) < IMG_W) {
            float4v t = *(const float4v*)(imgp + iy * IMG_W + cb);
            vv.x = t.x;
            vv.y = (q < 4) ? t.y : 0.f;       // mask patch-cols > 16 (chunk q=4)
            vv.z = (q < 4) ? t.z : 0.f;
            vv.w = (q < 4) ? t.w : 0.f;
        } else if (rowok) {                   // image col-edge (~2% of patches)
            const float* rp = imgp + iy * IMG_W;
#pragma unroll
            for (int e = 0; e < 4; ++e) {
                const int cp = (q << 2) + e;  // patch col
                const int ix = cb + e;        // image col
                float v = 0.f;
                if (cp <= 16 && (unsigned)ix < IMG_W) v = rp[ix];
                ((float*)&vv)[e] = v;
            }
        }
        *(float4v*)(ldst + a * LROW + (q << 2)) = vv;   // 16B-aligned LDS write
        ssum += (vv.x + vv.y) + (vv.z + vv.w);
        ssq  += (vv.x * vv.x + vv.y * vv.y) + (vv.z * vv.z + vv.w * vv.w);
    };

    // Phase 1: 170 slots over 3 iters (89% lane efficiency)
    gather(lane, imgA, mmA.x, mmA.y, lbase, sA, qA);
    {
        const int s  = 64 + lane;
        const bool w2 = (s >= 85);
        const int u  = w2 ? s - 85 : s;
        float ss = 0.f, sq = 0.f;
        gather(u, w2 ? imgB : imgA, w2 ? mmB.x : mmA.x, w2 ? mmB.y : mmA.y,
               lbase + (w2 ? PLANE : 0), ss, sq);
        if (w2) { sB += ss; qB += sq; } else { sA += ss; qA += sq; }
    }
    if (lane < 42) {
        gather(43 + lane, imgB, mmB.x, mmB.y, lbase + PLANE, sB, qB);
    }

    // wave-64 butterfly reduction (order-independent stats)
#pragma unroll
    for (int off = 32; off > 0; off >>= 1) {
        sA += __shfl_xor(sA, off, 64);
        qA += __shfl_xor(qA, off, 64);
        sB += __shfl_xor(sB, off, 64);
        qB += __shfl_xor(qB, off, 64);
    }

    const float meanA = sA * (1.0f / 289.0f);
    float varA = (qA - 289.0f * meanA * meanA) * (1.0f / 288.0f);
    varA = fmaxf(varA, 0.0f);
    const float invA = 1.0f / (sqrtf(varA) + 1e-4f);

    const float meanB = sB * (1.0f / 289.0f);
    float varB = (qB - 289.0f * meanB * meanB) * (1.0f / 288.0f);
    varB = fmaxf(varB, 0.0f);
    const float invB = 1.0f / (sqrtf(varB) + 1e-4f);

    // NO barrier: wave-private buffer, DS ops in-order within a wave.

    // Phase 2: transposed LDS read, per-patch coalesced stores (289 each)
    float* __restrict__ oA = out + (size_t)pairA * 578 + whichA * NPATCH;
    float* __restrict__ oB = out + (size_t)pairB * 578 + whichB * NPATCH;
    {
        const int j0 = lane << 2;             // 0..255, dwordx4
        float4v stA, stB;
#pragma unroll
        for (int e = 0; e < 4; ++e) {
            const int j = j0 + e;
            const int c = j / DPATCH;         // magic-mul
            const int a = j - c * DPATCH;
            const int lo = a * LROW + c;      // transposed LDS index
            ((float*)&stA)[e] = (lbase[lo] - meanA) * invA;
            ((float*)&stB)[e] = (lbase[PLANE + lo] - meanB) * invB;
        }
        __builtin_nontemporal_store(stA, (float4v*)(oA + j0));
        __builtin_nontemporal_store(stB, (float4v*)(oB + j0));
    }
    if (lane < 33) {                          // tails j = 256..288
        const int j = 256 + lane;
        const int c = j / DPATCH;
        const int a = j - c * DPATCH;
        const int lo = a * LROW + c;
        __builtin_nontemporal_store((lbase[lo] - meanA) * invA, oA + j);
        __builtin_nontemporal_store((lbase[PLANE + lo] - meanB) * invB, oB + j);
    }
}

// ---------------- fallback (R4 body, used only if d_ws too small) ----------------
__global__ __launch_bounds__(256) void extract_patch_pair(
    const float* __restrict__ img1,
    const float* __restrict__ img2,
    const int* __restrict__ matches,
    float* __restrict__ out)
{
    __shared__ __align__(16) float lds[4][2 * PLANE];
    const int lane  = threadIdx.x & 63;
    const int wslot = __builtin_amdgcn_readfirstlane(threadIdx.x >> 6);
    const int pair  = blockIdx.x * 4 + wslot;
    const int b     = pair >> 12;
    const int4 mm = *(const int4*)(matches + (size_t)pair * 4);
    const size_t ioff = (size_t)b * HW;
    const float* __restrict__ imgb1 = img1 + ioff;
    const float* __restrict__ imgb2 = img2 + ioff;
    float* __restrict__ lbase = &lds[wslot][0];
    float sA = 0.f, qA = 0.f, sB = 0.f, qB = 0.f;
    auto gather = [&](int u, const float* __restrict__ imgp, int mx, int my,
                      float* __restrict__ ldst, float& ssum, float& ssq) {
        const int a  = u / 5;
        const int q  = u - a * 5;
        const int iy = my + a - RAD;
        const int cb = mx + (q << 2) - RAD;
        float4v vv = {0.f, 0.f, 0.f, 0.f};
        const bool rowok = ((unsigned)iy < IMG_H);
        if (rowok && cb >= 0 && (cb + 3) < IMG_W) {
            float4v t = *(const float4v*)(imgp + iy * IMG_W + cb);
            vv.x = t.x;
            vv.y = (q < 4) ? t.y : 0.f;
            vv.z = (q < 4) ? t.z : 0.f;
            vv.w = (q < 4) ? t.w : 0.f;
        } else if (rowok) {
            const float* rp = imgp + iy * IMG_W;
#pragma unroll
            for (int e = 0; e < 4; ++e) {
                const int cp = (q << 2) + e;
                const int ix = cb + e;
                float v = 0.f;
                if (cp <= 16 && (unsigned)ix < IMG_W) v = rp[ix];
                ((float*)&vv)[e] = v;
            }
        }
        *(float4v*)(ldst + a * LROW + (q << 2)) = vv;
        ssum += (vv.x + vv.y) + (vv.z + vv.w);
        ssq  += (vv.x * vv.x + vv.y * vv.y) + (vv.z * vv.z + vv.w * vv.w);
    };
    gather(lane, imgb1, mm.x, mm.y, lbase, sA, qA);
    {
        const int s  = 64 + lane;
        const bool w2 = (s >= 85);
        const int u  = w2 ? s - 85 : s;
        float ss = 0.f, sq = 0.f;
        gather(u, w2 ? imgb2 : imgb1, w2 ? mm.z : mm.x, w2 ? mm.w : mm.y,
               lbase + (w2 ? PLANE : 0), ss, sq);
        if (w2) { sB += ss; qB += sq; } else { sA += ss; qA += sq; }
    }
    if (lane < 42) gather(43 + lane, imgb2, mm.z, mm.w, lbase + PLANE, sB, qB);
#pragma unroll
    for (int off = 32; off > 0; off >>= 1) {
        sA += __shfl_xor(sA, off, 64);
        qA += __shfl_xor(qA, off, 64);
        sB += __shfl_xor(sB, off, 64);
        qB += __shfl_xor(qB, off, 64);
    }
    const float meanA = sA * (1.0f / 289.0f);
    float varA = (qA - 289.0f * meanA * meanA) * (1.0f / 288.0f);
    varA = fmaxf(varA, 0.0f);
    const float invA = 1.0f / (sqrtf(varA) + 1e-4f);
    const float meanB = sB * (1.0f / 289.0f);
    float varB = (qB - 289.0f * meanB * meanB) * (1.0f / 288.0f);
    varB = fmaxf(varB, 0.0f);
    const float invB = 1.0f / (sqrtf(varB) + 1e-4f);
    float* __restrict__ o = out + (size_t)pair * 578;
#pragma unroll
    for (int k = 0; k < 2; ++k) {
        const int j0 = (k << 8) + (lane << 2);
        float4v st;
#pragma unroll
        for (int e = 0; e < 4; ++e) {
            const int j   = j0 + e;
            const bool w2 = (j >= NPATCH);
            const int jj  = w2 ? j - NPATCH : j;
            const int c   = jj / DPATCH;
            const int a   = jj - c * DPATCH;
            const float v = lbase[(w2 ? PLANE : 0) + a * LROW + c];
            ((float*)&st)[e] = (v - (w2 ? meanB : meanA)) * (w2 ? invB : invA);
        }
        __builtin_nontemporal_store(st, (float4v*)(o + j0));
    }
    if (lane < 33) {
        const int j0 = 512 + (lane << 1);
        float2v st;
#pragma unroll
        for (int e = 0; e < 2; ++e) {
            const int jj = j0 + e - NPATCH;
            const int c  = jj / DPATCH;
            const int a  = jj - c * DPATCH;
            ((float*)&st)[e] = (lbase[PLANE + a * LROW + c] - meanB) * invB;
        }
        __builtin_nontemporal_store(st, (float2v*)(o + j0));
    }
}

extern "C" void kernel_launch(void* const* d_in, const int* in_sizes, int n_in,
                              void* d_out, int out_size, void* d_ws, size_t ws_size,
                              hipStream_t stream) {
    const float* img1  = (const float*)d_in[0];
    const float* img2  = (const float*)d_in[1];
    const int* matches = (const int*)d_in[2];
    float* out         = (float*)d_out;

    const size_t need = (size_t)(NBINS * 2 + NPT) * sizeof(unsigned); // 288 KB
    if (d_ws != nullptr && ws_size >= need) {
        unsigned* cnt = (unsigned*)d_ws;
        unsigned* cur = cnt + NBINS;
        unsigned* srt = cur + NBINS;
        hipLaunchKernelGGL(zero_counts, dim3(NBINS / 256), dim3(256), 0, stream, cnt);
        hipLaunchKernelGGL(count_bins, dim3(NPT / 256), dim3(256), 0, stream,
                           matches, cnt);
        hipLaunchKernelGGL(scan_bins, dim3(1), dim3(256), 0, stream, cnt, cur);
        hipLaunchKernelGGL(scatter_ids, dim3(NPT / 256), dim3(256), 0, stream,
                           matches, cur, srt);
        hipLaunchKernelGGL(extract_patch_sorted, dim3(8192), dim3(256), 0, stream,
                           img1, img2, matches, srt, out);
    } else {
        hipLaunchKernelGGL(extract_patch_pair, dim3(8192), dim3(256), 0, stream,
                           img1, img2, matches, out);
    }
}

// Round 8
// 149.611 us; speedup vs baseline: 1.0471x; 1.0471x over previous
//
#include <hip/hip_runtime.h>

// B=8, H=W=1024, N=4096, R=8 -> d=17, patch=289, out (B,N,578) f32.
// p[t=2*pair+which, j] = img_which[b, my + j%17 - 8, mx + j/17 - 8] (0-pad OOB)
// normalized per 289-vec: (p - mean) / (std_ddof1 + 1e-4). out + t*289.
//
// R7 post-mortem: sorting cut FETCH 90->32MB with ZERO time gain -> the floor
// is divergent-VMEM line serialization in the CU memory pipe (hit/miss level
// irrelevant). R8 eliminates divergent global reads entirely: one block per
// 64x64 bin stages the 80x80 halo region into LDS via contiguous float4
// loads (streaming), patches gather from LDS (stride 81 -> <=2-way, free).
// Aux: memset + one atomic-append kernel (fixed-capacity bins + overflow).

#define IMG_H 1024
#define IMG_W 1024
#define HW (IMG_H * IMG_W)
#define DPATCH 17
#define NPATCH 289
#define RAD 8
#define NPT 65536             // total patches
#define NBINS 4096            // 8 b x 2 which x 16 x 16 (64-px cells)
#define SLOTC 40              // bin capacity (Poisson mean 16; overflow handled)
#define OVFCAP 4096
#define RSTRIDE 81            // LDS region stride (odd -> conflict-free reads)
#define RROWS 80

// ws layout (u32 indices):
#define WS_CNT  0                       // [0,4096) bin counts
#define WS_OVFN 4096                    // overflow count
#define WS_OVF  4104                    // [4104, 4104+OVFCAP) overflow ids
#define WS_SLOT (4104 + OVFCAP)         // [.., ..+NBINS*SLOTC) slot ids
#define WS_TOTAL (WS_SLOT + NBINS * SLOTC)

typedef float float4v __attribute__((ext_vector_type(4)));
typedef float float2v __attribute__((ext_vector_type(2)));

// ---------------- aux: append patch ids into bins ----------------
__global__ __launch_bounds__(256) void bin_append(
    const int* __restrict__ matches, unsigned* __restrict__ ws)
{
    const int t = blockIdx.x * 256 + threadIdx.x;      // 0..65535
    const int pair = t >> 1, which = t & 1;
    const int2 mm = *(const int2*)(matches + pair * 4 + (which << 1));
    const int b = pair >> 12;
    const int bin = (((b << 1) | which) << 8) | ((mm.y >> 6) << 4) | (mm.x >> 6);
    const unsigned pos = atomicAdd(&ws[WS_CNT + bin], 1u);
    if (pos < SLOTC) {
        ws[WS_SLOT + bin * SLOTC + pos] = (unsigned)t;
    } else {
        const unsigned op = atomicAdd(&ws[WS_OVFN], 1u);
        if (op < OVFCAP) ws[WS_OVF + op] = (unsigned)t;
    }
}

// ---------------- main: one block per bin, LDS-staged gather ----------------
__global__ __launch_bounds__(256) void extract_patch_binned(
    const float* __restrict__ img1, const float* __restrict__ img2,
    const int* __restrict__ matches, const unsigned* __restrict__ ws,
    float* __restrict__ out)
{
    __shared__ float reg[RROWS * RSTRIDE];   // 80x81 f32 = 25.9 KB
    __shared__ int binT[SLOTC], binX[SLOTC], binY[SLOTC];

    const int tid   = threadIdx.x;
    const int lane  = tid & 63;
    const int wslot = tid >> 6;
    const int bin   = blockIdx.x;

    if (bin < NBINS) {
        const int cnt0 = (int)ws[WS_CNT + bin];
        const int cnt  = cnt0 < SLOTC ? cnt0 : SLOTC;

        // ---- stage 80x80 halo region, contiguous float4 loads (streaming) ----
        // halo = 8 px = exactly 2 float4 chunks -> chunks are all-in or all-out,
        // never partial. 1600 chunks (80 rows x 20), 7 iters of 256 threads.
        const int plane = bin >> 8;
        const float* __restrict__ img =
            ((plane & 1) ? img2 : img1) + (size_t)(plane >> 1) * HW;
        const int by0 = ((bin >> 4) & 15) << 6;
        const int bx0 = (bin & 15) << 6;
#pragma unroll
        for (int k = 0; k < 7; ++k) {
            const int m = tid + (k << 8);
            if (m < 1600) {
                const int r  = m / 20;                 // magic-mul
                const int cq = m - r * 20;
                const int gy = by0 - 8 + r;
                const int gx = bx0 - 8 + (cq << 2);    // 16B-aligned
                float4v v = {0.f, 0.f, 0.f, 0.f};
                if ((unsigned)gy < IMG_H && (unsigned)gx < IMG_W)
                    v = *(const float4v*)(img + gy * IMG_W + gx);
                const int lb = r * RSTRIDE + (cq << 2);
                reg[lb] = v.x; reg[lb+1] = v.y; reg[lb+2] = v.z; reg[lb+3] = v.w;
            }
        }
        // ---- bin meta: patch ids + coords (coalesced, before barrier) ----
        if (tid < cnt) {
            const int t = (int)ws[WS_SLOT + bin * SLOTC + tid];
            const int2 mm = *(const int2*)(matches + (t >> 1) * 4 + ((t & 1) << 1));
            binT[tid] = t; binX[tid] = mm.x; binY[tid] = mm.y;
        }
        __syncthreads();
        if (cnt == 0) return;                          // uniform, after barrier

        // per-lane invariants: out j -> region offset pr*81 + pc
        int pofs[4];
#pragma unroll
        for (int e = 0; e < 4; ++e) {
            const int j  = (lane << 2) + e;            // 0..255
            const int pc = j / DPATCH;
            const int pr = j - pc * DPATCH;
            pofs[e] = pr * RSTRIDE + pc;
        }
        int ptail = 0;
        if (lane < 33) {
            const int j  = 256 + lane;                 // 256..288
            const int pc = j / DPATCH;
            const int pr = j - pc * DPATCH;
            ptail = pr * RSTRIDE + pc;
        }

        // ---- one patch per wave per round; all gathers from LDS ----
        for (int p = wslot; p < cnt; p += 4) {
            const int t  = binT[p];                    // uniform broadcast reads
            const int mx = binX[p];
            const int my = binY[p];
            const int base = (my - by0) * RSTRIDE + (mx - bx0);

            float v[4]; float sum = 0.f, sq = 0.f;
#pragma unroll
            for (int e = 0; e < 4; ++e) {
                v[e] = reg[base + pofs[e]];            // <=2-way banks (free)
                sum += v[e]; sq += v[e] * v[e];
            }
            float vt = 0.f;
            if (lane < 33) vt = reg[base + ptail];
            sum += vt; sq += vt * vt;

#pragma unroll
            for (int off = 32; off > 0; off >>= 1) {
                sum += __shfl_xor(sum, off, 64);
                sq  += __shfl_xor(sq,  off, 64);
            }
            const float mean = sum * (1.0f / 289.0f);
            float var = (sq - 289.0f * mean * mean) * (1.0f / 288.0f);
            var = fmaxf(var, 0.0f);
            const float inv = 1.0f / (sqrtf(var) + 1e-4f);

            float* __restrict__ o = out + (size_t)t * NPATCH;  // t*289 exact
            float4v st;
            st.x = (v[0] - mean) * inv; st.y = (v[1] - mean) * inv;
            st.z = (v[2] - mean) * inv; st.w = (v[3] - mean) * inv;
            __builtin_nontemporal_store(st, (float4v*)(o + (lane << 2)));
            if (lane < 33)
                __builtin_nontemporal_store((vt - mean) * inv, o + 256 + lane);
        }
    } else {
        // ---- overflow block (expected ~0 entries): direct-gather path ----
        unsigned n = ws[WS_OVFN];
        if (n > OVFCAP) n = OVFCAP;
        for (unsigned i = wslot; i < n; i += 4) {
            const int t = (int)ws[WS_OVF + i];
            const int pair = t >> 1, which = t & 1;
            const int2 mm = *(const int2*)(matches + pair * 4 + (which << 1));
            const float* __restrict__ img =
                (which ? img2 : img1) + (size_t)(pair >> 12) * HW;
            float v[5]; float sum = 0.f, sq = 0.f;
#pragma unroll
            for (int k = 0; k < 5; ++k) {
                const int j = lane + (k << 6);
                float val = 0.f;
                if (j < NPATCH) {
                    const int pc = j / DPATCH;
                    const int pr = j - pc * DPATCH;
                    const int iy = mm.y + pr - RAD;
                    const int ix = mm.x + pc - RAD;
                    if ((unsigned)iy < IMG_H && (unsigned)ix < IMG_W)
                        val = img[iy * IMG_W + ix];
                }
                v[k] = val; sum += val; sq += val * val;
            }
#pragma unroll
            for (int off = 32; off > 0; off >>= 1) {
                sum += __shfl_xor(sum, off, 64);
                sq  += __shfl_xor(sq,  off, 64);
            }
            const float mean = sum * (1.0f / 289.0f);
            float var = (sq - 289.0f * mean * mean) * (1.0f / 288.0f);
            var = fmaxf(var, 0.0f);
            const float inv = 1.0f / (sqrtf(var) + 1e-4f);
            float* __restrict__ o = out + (size_t)t * NPATCH;
#pragma unroll
            for (int k = 0; k < 5; ++k) {
                const int j = lane + (k << 6);
                if (j < NPATCH) o[j] = (v[k] - mean) * inv;
            }
        }
    }
}

// ---------------- fallback (R4 body) if d_ws too small ----------------
#define LROW 20
#define PLANE (DPATCH * LROW)
__global__ __launch_bounds__(256) void extract_patch_pair(
    const float* __restrict__ img1,
    const float* __restrict__ img2,
    const int* __restrict__ matches,
    float* __restrict__ out)
{
    __shared__ __align__(16) float lds[4][2 * PLANE];
    const int lane  = threadIdx.x & 63;
    const int wslot = __builtin_amdgcn_readfirstlane(threadIdx.x >> 6);
    const int pair  = blockIdx.x * 4 + wslot;
    const int b     = pair >> 12;
    const int4 mm = *(const int4*)(matches + (size_t)pair * 4);
    const size_t ioff = (size_t)b * HW;
    const float* __restrict__ imgb1 = img1 + ioff;
    const float* __restrict__ imgb2 = img2 + ioff;
    float* __restrict__ lbase = &lds[wslot][0];
    float sA = 0.f, qA = 0.f, sB = 0.f, qB = 0.f;
    auto gather = [&](int u, const float* __restrict__ imgp, int mx, int my,
                      float* __restrict__ ldst, float& ssum, float& ssq) {
        const int a  = u / 5;
        const int q  = u - a * 5;
        const int iy = my + a - RAD;
        const int cb = mx + (q << 2) - RAD;
        float4v vv = {0.f, 0.f, 0.f, 0.f};
        const bool rowok = ((unsigned)iy < IMG_H);
        if (rowok && cb >= 0 && (cb + 3) < IMG_W) {
            float4v t = *(const float4v*)(imgp + iy * IMG_W + cb);
            vv.x = t.x;
            vv.y = (q < 4) ? t.y : 0.f;
            vv.z = (q < 4) ? t.z : 0.f;
            vv.w = (q < 4) ? t.w : 0.f;
        } else if (rowok) {
            const float* rp = imgp + iy * IMG_W;
#pragma unroll
            for (int e = 0; e < 4; ++e) {
                const int cp = (q << 2) + e;
                const int ix = cb + e;
                float v = 0.f;
                if (cp <= 16 && (unsigned)ix < IMG_W) v = rp[ix];
                ((float*)&vv)[e] = v;
            }
        }
        *(float4v*)(ldst + a * LROW + (q << 2)) = vv;
        ssum += (vv.x + vv.y) + (vv.z + vv.w);
        ssq  += (vv.x * vv.x + vv.y * vv.y) + (vv.z * vv.z + vv.w * vv.w);
    };
    gather(lane, imgb1, mm.x, mm.y, lbase, sA, qA);
    {
        const int s  = 64 + lane;
        const bool w2 = (s >= 85);
        const int u  = w2 ? s - 85 : s;
        float ss = 0.f, sq = 0.f;
        gather(u, w2 ? imgb2 : imgb1, w2 ? mm.z : mm.x, w2 ? mm.w : mm.y,
               lbase + (w2 ? PLANE : 0), ss, sq);
        if (w2) { sB += ss; qB += sq; } else { sA += ss; qA += sq; }
    }
    if (lane < 42) gather(43 + lane, imgb2, mm.z, mm.w, lbase + PLANE, sB, qB);
#pragma unroll
    for (int off = 32; off > 0; off >>= 1) {
        sA += __shfl_xor(sA, off, 64);
        qA += __shfl_xor(qA, off, 64);
        sB += __shfl_xor(sB, off, 64);
        qB += __shfl_xor(qB, off, 64);
    }
    const float meanA = sA * (1.0f / 289.0f);
    float varA = (qA - 289.0f * meanA * meanA) * (1.0f / 288.0f);
    varA = fmaxf(varA, 0.0f);
    const float invA = 1.0f / (sqrtf(varA) + 1e-4f);
    const float meanB = sB * (1.0f / 289.0f);
    float varB = (qB - 289.0f * meanB * meanB) * (1.0f / 288.0f);
    varB = fmaxf(varB, 0.0f);
    const float invB = 1.0f / (sqrtf(varB) + 1e-4f);
    float* __restrict__ o = out + (size_t)pair * 578;
#pragma unroll
    for (int k = 0; k < 2; ++k) {
        const int j0 = (k << 8) + (lane << 2);
        float4v st;
#pragma unroll
        for (int e = 0; e < 4; ++e) {
            const int j   = j0 + e;
            const bool w2 = (j >= NPATCH);
            const int jj  = w2 ? j - NPATCH : j;
            const int c   = jj / DPATCH;
            const int a   = jj - c * DPATCH;
            const float v = lbase[(w2 ? PLANE : 0) + a * LROW + c];
            ((float*)&st)[e] = (v - (w2 ? meanB : meanA)) * (w2 ? invB : invA);
        }
        __builtin_nontemporal_store(st, (float4v*)(o + j0));
    }
    if (lane < 33) {
        const int j0 = 512 + (lane << 1);
        float2v st;
#pragma unroll
        for (int e = 0; e < 2; ++e) {
            const int jj = j0 + e - NPATCH;
            const int c  = jj / DPATCH;
            const int a  = jj - c * DPATCH;
            ((float*)&st)[e] = (lbase[PLANE + a * LROW + c] - meanB) * invB;
        }
        __builtin_nontemporal_store(st, (float2v*)(o + j0));
    }
}

extern "C" void kernel_launch(void* const* d_in, const int* in_sizes, int n_in,
                              void* d_out, int out_size, void* d_ws, size_t ws_size,
                              hipStream_t stream) {
    const float* img1  = (const float*)d_in[0];
    const float* img2  = (const float*)d_in[1];
    const int* matches = (const int*)d_in[2];
    float* out         = (float*)d_out;

    const size_t need = (size_t)WS_TOTAL * sizeof(unsigned);   // ~690 KB
    if (d_ws != nullptr && ws_size >= need) {
        unsigned* ws = (unsigned*)d_ws;
        // zero bin counts + overflow count
        hipMemsetAsync(ws, 0, (WS_OVFN + 8) * sizeof(unsigned), stream);
        hipLaunchKernelGGL(bin_append, dim3(NPT / 256), dim3(256), 0, stream,
                           matches, ws);
        hipLaunchKernelGGL(extract_patch_binned, dim3(NBINS + 1), dim3(256), 0,
                           stream, img1, img2, matches, ws, out);
    } else {
        hipLaunchKernelGGL(extract_patch_pair, dim3(8192), dim3(256), 0, stream,
                           img1, img2, matches, out);
    }
}

// Round 9
// 139.526 us; speedup vs baseline: 1.1228x; 1.0723x over previous
//
#include <hip/hip_runtime.h>

// B=8, H=W=1024, N=4096, R=8 -> d=17, patch=289, out (B,N,578) f32.
// p1[b,n,j] = img1[b, m1 + j%17 - 8, m0 + j/17 - 8]; p2 likewise with (m2,m3).
// normalize each 289-vector: (p - mean) / (std_ddof1 + 1e-4).
//
// Session ledger: 9 designs all land 45-50us; counters always moved as
// predicted, time didn't. Scattered side of HBM traffic sets the pace ->
// keep R4 (sequential writes, minimal scattered reads). R9 = R4 with ONE
// change: plain stores instead of nontemporal, letting the 256MB LLC absorb
// the 76MB output (images 64MB + out 76MB << 256MB) instead of forcing a
// synchronous HBM drain inside the dispatch.

#define IMG_H 1024
#define IMG_W 1024
#define DPATCH 17
#define NPATCH 289
#define RAD 8
#define LROW 20               // LDS row stride (5 float4 chunks, 16B aligned)
#define PLANE (DPATCH * LROW) // 340 floats per patch plane

typedef float float4v __attribute__((ext_vector_type(4)));
typedef float float2v __attribute__((ext_vector_type(2)));

__global__ __launch_bounds__(256) void extract_patch_kernel(
    const float* __restrict__ img1,
    const float* __restrict__ img2,
    const int* __restrict__ matches,
    float* __restrict__ out)
{
    // per-wave private transpose buffer: 2 patch planes (2720 B), 4 waves/block
    __shared__ __align__(16) float lds[4][2 * PLANE];

    const int lane  = threadIdx.x & 63;
    // force wave-uniform -> SGPR, so matches read compiles to s_load_dwordx4
    const int wslot = __builtin_amdgcn_readfirstlane(threadIdx.x >> 6);
    const int pair  = blockIdx.x * 4 + wslot;   // b*4096 + n, scalar
    const int b     = pair >> 12;               // scalar

    const int4 mm = *(const int4*)(matches + (size_t)pair * 4); // scalar load
    const int mx1 = mm.x, my1 = mm.y, mx2 = mm.z, my2 = mm.w;

    const size_t ioff = (size_t)b * (IMG_H * IMG_W);
    const float* __restrict__ imgb1 = img1 + ioff;
    const float* __restrict__ imgb2 = img2 + ioff;

    float* __restrict__ lbase = &lds[wslot][0];

    float sA = 0.f, qA = 0.f, sB = 0.f, qB = 0.f;

    // gather one slot u = a*5 + q of one patch: image row my+a-8, cols mx+4q-8..+3
    auto gather = [&](int u, const float* __restrict__ imgp, int mx, int my,
                      float* __restrict__ ldst, float& ssum, float& ssq) {
        const int a  = u / 5;                 // magic-mul
        const int q  = u - a * 5;
        const int iy = my + a - RAD;
        const int cb = mx + (q << 2) - RAD;
        float4v vv = {0.f, 0.f, 0.f, 0.f};
        const bool rowok = ((unsigned)iy < IMG_H);
        if (rowok && cb >= 0 && (cb + 3) < IMG_W) {
            float4v t = *(const float4v*)(imgp + iy * IMG_W + cb);
            vv.x = t.x;
            vv.y = (q < 4) ? t.y : 0.f;       // mask patch-cols > 16 (chunk q=4)
            vv.z = (q < 4) ? t.z : 0.f;
            vv.w = (q < 4) ? t.w : 0.f;
        } else if (rowok) {                   // image col-edge (~2% of patches)
            const float* rp = imgp + iy * IMG_W;
#pragma unroll
            for (int e = 0; e < 4; ++e) {
                const int cp = (q << 2) + e;  // patch col
                const int ix = cb + e;        // image col
                float v = 0.f;
                if (cp <= 16 && (unsigned)ix < IMG_W) v = rp[ix];
                ((float*)&vv)[e] = v;
            }
        }
        *(float4v*)(ldst + a * LROW + (q << 2)) = vv;   // 16B-aligned LDS write
        ssum += (vv.x + vv.y) + (vv.z + vv.w);
        ssq  += (vv.x * vv.x + vv.y * vv.y) + (vv.z * vv.z + vv.w * vv.w);
    };

    // ---- Phase 1: 170 slots over 3 iters (89% lane efficiency) ----
    // iter0: slots 0..63   -> patch1 u=0..63
    gather(lane, imgb1, mx1, my1, lbase, sA, qA);

    // iter1: slots 64..127 -> patch1 u=64..84 (lanes 0..20), patch2 u=0..42
    {
        const int s  = 64 + lane;
        const bool w2 = (s >= 85);
        const int u  = w2 ? s - 85 : s;
        const float* imgp = w2 ? imgb2 : imgb1;
        const int mx = w2 ? mx2 : mx1;
        const int my = w2 ? my2 : my1;
        float ss = 0.f, sq = 0.f;
        gather(u, imgp, mx, my, lbase + (w2 ? PLANE : 0), ss, sq);
        if (w2) { sB += ss; qB += sq; } else { sA += ss; qA += sq; }
    }

    // iter2: slots 128..169 -> patch2 u=43..84 (lanes 0..41)
    if (lane < 42) {
        gather(43 + lane, imgb2, mx2, my2, lbase + PLANE, sB, qB);
    }

    // ---- wave-64 butterfly reduction, both patches (order-independent) ----
#pragma unroll
    for (int off = 32; off > 0; off >>= 1) {
        sA += __shfl_xor(sA, off, 64);
        qA += __shfl_xor(qA, off, 64);
        sB += __shfl_xor(sB, off, 64);
        qB += __shfl_xor(qB, off, 64);
    }

    const float meanA = sA * (1.0f / 289.0f);
    float varA = (qA - 289.0f * meanA * meanA) * (1.0f / 288.0f);
    varA = fmaxf(varA, 0.0f);
    const float invA = 1.0f / (sqrtf(varA) + 1e-4f);

    const float meanB = sB * (1.0f / 289.0f);
    float varB = (qB - 289.0f * meanB * meanB) * (1.0f / 288.0f);
    varB = fmaxf(varB, 0.0f);
    const float invB = 1.0f / (sqrtf(varB) + 1e-4f);

    // NO barrier: buffer is wave-private, DS ops from one wave are in-order.

    // ---- Phase 2: transposed LDS read, coalesced wide stores (578 floats) ----
    // out[j]: which = j>=289; jj = j - 289*which; val = plane[(jj%17)*20 + jj/17]
    // Plain (cacheable) stores: LLC absorbs the 76MB output stream.
    float* __restrict__ o = out + (size_t)pair * 578;
#pragma unroll
    for (int k = 0; k < 2; ++k) {
        const int j0 = (k << 8) + (lane << 2);   // 0..511
        float4v st;
#pragma unroll
        for (int e = 0; e < 4; ++e) {
            const int j   = j0 + e;
            const bool w2 = (j >= NPATCH);
            const int jj  = w2 ? j - NPATCH : j;
            const int c   = jj / DPATCH;          // magic-mul
            const int a   = jj - c * DPATCH;
            const float v = lbase[(w2 ? PLANE : 0) + a * LROW + c];
            ((float*)&st)[e] = (v - (w2 ? meanB : meanA)) * (w2 ? invB : invA);
        }
        *(float4v*)(o + j0) = st;
    }
    // tail j = 512..577: 66 elements = 33 lanes x dwordx2 (8B-aligned)
    if (lane < 33) {
        const int j0 = 512 + (lane << 1);
        float2v st;
#pragma unroll
        for (int e = 0; e < 2; ++e) {
            const int jj = j0 + e - NPATCH;       // all patch2 (512 >= 289)
            const int c  = jj / DPATCH;
            const int a  = jj - c * DPATCH;
            ((float*)&st)[e] = (lbase[PLANE + a * LROW + c] - meanB) * invB;
        }
        *(float2v*)(o + j0) = st;
    }
}

extern "C" void kernel_launch(void* const* d_in, const int* in_sizes, int n_in,
                              void* d_out, int out_size, void* d_ws, size_t ws_size,
                              hipStream_t stream) {
    const float* img1  = (const float*)d_in[0];
    const float* img2  = (const float*)d_in[1];
    const int* matches = (const int*)d_in[2];
    float* out         = (float*)d_out;

    // one wave per (b,n) pair: 8*4096 = 32768 pairs, 4 waves/block -> 8192 blocks
    const int n_pairs = 8 * 4096;
    dim3 block(256);
    dim3 grid(n_pairs / 4);
    hipLaunchKernelGGL(extract_patch_kernel, grid, block, 0, stream,
                       img1, img2, matches, out);
}